// Round 2
// baseline (1093.359 us; speedup 1.0000x reference)
//
#include <hip/hip_runtime.h>
#include <math.h>

#define L_SEQ 8192
#define NFFT  16384
#define CCH   768
#define BB    4
#define EDIM  33
#define ODIM  64
#define BLK   512
#define NPAIR (NFFT / 16)

// ---------- complex helpers ----------
__device__ __forceinline__ float2 cadd(float2 a, float2 b) { return make_float2(a.x + b.x, a.y + b.y); }
__device__ __forceinline__ float2 csub(float2 a, float2 b) { return make_float2(a.x - b.x, a.y - b.y); }
__device__ __forceinline__ float2 cmul(float2 a, float2 b) {
  return make_float2(fmaf(a.x, b.x, -a.y * b.y), fmaf(a.x, b.y, a.y * b.x));
}
__device__ __forceinline__ float2 cconj(float2 a) { return make_float2(a.x, -a.y); }

// LDS bank-conflict swizzle (bijective within 256-entry blocks)
__device__ __forceinline__ int swz(int i) { return i ^ ((i >> 4) & 15); }

// reverse 7 base-4 digits of a 14-bit index
__device__ __forceinline__ int rev4_14(int v) {
  int r = 0;
#pragma unroll
  for (int i = 0; i < 7; ++i) { r = (r << 2) | (v & 3); v >>= 2; }
  return r;
}

// ---------- twiddle table W_N^r = exp(-2*pi*i*r/N) ----------
__global__ void twiddle_kernel(float2* __restrict__ tw) {
  int r = blockIdx.x * blockDim.x + threadIdx.x;
  if (r < NFFT) {
    float th = (float)(6.283185307179586476925286766559 / (double)NFFT) * (float)r;
    float s, c;
    sincosf(th, &s, &c);
    tw[r] = make_float2(c, -s);
  }
}

// ---------- MLP: h[o][l] = 3x(Dense+Sin) of z[l] ----------
__global__ __launch_bounds__(64) void mlp_kernel(
    const float* __restrict__ z,      // [L, 33]
    const float* __restrict__ freq,   // [64]
    const float* __restrict__ w0, const float* __restrict__ b0,
    const float* __restrict__ w1, const float* __restrict__ b1,
    const float* __restrict__ w2, const float* __restrict__ b2,
    float* __restrict__ h)            // [64][L]
{
  int l = blockIdx.x * 64 + threadIdx.x;
  float zb[EDIM];
#pragma unroll
  for (int e = 0; e < EDIM; ++e) zb[e] = z[l * EDIM + e];

  float ha[ODIM], hb[ODIM];
#pragma unroll
  for (int o = 0; o < ODIM; ++o) {
    float acc = b0[o];
#pragma unroll
    for (int e = 0; e < EDIM; ++e) acc = fmaf(zb[e], w0[e * ODIM + o], acc);
    ha[o] = sinf(freq[o] * acc);
  }
#pragma unroll
  for (int o = 0; o < ODIM; ++o) {
    float acc = b1[o];
#pragma unroll
    for (int i = 0; i < ODIM; ++i) acc = fmaf(ha[i], w1[i * ODIM + o], acc);
    hb[o] = sinf(freq[o] * acc);
  }
#pragma unroll
  for (int o = 0; o < ODIM; ++o) {
    float acc = b2[o];
#pragma unroll
    for (int i = 0; i < ODIM; ++i) acc = fmaf(hb[i], w2[i * ODIM + o], acc);
    h[o * L_SEQ + l] = sinf(freq[o] * acc);
  }
}

// ---------- k[c][l] = (h . wout[:,c]) * exp(-t[l]*|deltas[c]|) ----------
#define KT_L 128
#define KT_C 64
__global__ __launch_bounds__(KT_L) void kout_kernel(
    const float* __restrict__ h,      // [64][L]
    const float* __restrict__ wout,   // [64][768]
    const float* __restrict__ t,      // [L]
    const float* __restrict__ deltas, // [768]
    float* __restrict__ k)            // [768][L]
{
  __shared__ float hT[ODIM][KT_L];   // 32 KB
  __shared__ float wT[ODIM][KT_C];   // 16 KB
  const int lb = blockIdx.x % (L_SEQ / KT_L);
  const int cb = blockIdx.x / (L_SEQ / KT_L);
  const int l0 = lb * KT_L, c0 = cb * KT_C;
  const int tid = threadIdx.x;
  for (int i = tid; i < ODIM * KT_L; i += KT_L) {
    int o = i / KT_L, ll = i % KT_L;
    hT[o][ll] = h[o * L_SEQ + l0 + ll];
  }
  for (int i = tid; i < ODIM * KT_C; i += KT_L) {
    int o = i / KT_C, cc = i % KT_C;
    wT[o][cc] = wout[o * CCH + c0 + cc];
  }
  __syncthreads();
  float hv[ODIM];
#pragma unroll
  for (int o = 0; o < ODIM; ++o) hv[o] = hT[o][tid];
  const float tl = t[l0 + tid];
  for (int c = 0; c < KT_C; ++c) {
    float acc = 0.f;
#pragma unroll
    for (int o = 0; o < ODIM; ++o) acc = fmaf(hv[o], wT[o][c], acc);
    float mod = expf(-tl * fabsf(deltas[c0 + c]));
    k[(size_t)(c0 + c) * L_SEQ + l0 + tid] = acc * mod;
  }
}

// ---------- in-LDS FFT, radix-4 DIF with fused radix-16 rounds ----------
// forward: natural -> base4-digit-reversed
__device__ __forceinline__ void fft_fwd(float2* Z, const float2* __restrict__ tw, int tid) {
#pragma unroll
  for (int mlog = 12; mlog >= 4; mlog -= 4) {   // fused stage pairs (m, m/4)
    const int m = 1 << mlog, q = m >> 2;
    const int tsA = NFFT >> (mlog + 2);
    const int tsB = NFFT >> mlog;
#pragma unroll
    for (int j = tid; j < NPAIR; j += BLK) {
      const int u = j & (q - 1);
      const int g = j >> (mlog - 2);
      const int base = (g << (mlog + 2)) + u;
      float2 e[4][4];
#pragma unroll
      for (int s = 0; s < 4; ++s)
#pragma unroll
        for (int t = 0; t < 4; ++t) e[s][t] = Z[swz(base + s * m + t * q)];
      // stage A: radix-4 DIF over s (span m), exponent (u+t*q)*tsA
#pragma unroll
      for (int t = 0; t < 4; ++t) {
        float2 a = cadd(e[0][t], e[2][t]), b = csub(e[0][t], e[2][t]);
        float2 cc = cadd(e[1][t], e[3][t]), d = csub(e[1][t], e[3][t]);
        float2 w1 = tw[(u + t * q) * tsA];
        float2 w2 = cmul(w1, w1);
        float2 w3 = cmul(w2, w1);
        e[0][t] = cadd(a, cc);
        e[1][t] = cmul(make_float2(b.x + d.y, b.y - d.x), w1);
        e[2][t] = cmul(csub(a, cc), w2);
        e[3][t] = cmul(make_float2(b.x - d.y, b.y + d.x), w3);
      }
      // stage B: radix-4 DIF over t (span q), exponent u*tsB (same for all s)
      {
        float2 w1 = tw[u * tsB];
        float2 w2 = cmul(w1, w1);
        float2 w3 = cmul(w2, w1);
#pragma unroll
        for (int s = 0; s < 4; ++s) {
          float2 a = cadd(e[s][0], e[s][2]), b = csub(e[s][0], e[s][2]);
          float2 cc = cadd(e[s][1], e[s][3]), d = csub(e[s][1], e[s][3]);
          e[s][0] = cadd(a, cc);
          e[s][1] = cmul(make_float2(b.x + d.y, b.y - d.x), w1);
          e[s][2] = cmul(csub(a, cc), w2);
          e[s][3] = cmul(make_float2(b.x - d.y, b.y + d.x), w3);
        }
      }
#pragma unroll
      for (int s = 0; s < 4; ++s)
#pragma unroll
        for (int t = 0; t < 4; ++t) Z[swz(base + s * m + t * q)] = e[s][t];
    }
    __syncthreads();
  }
  // final radix-4 stage (span 1, twiddle-free)
#pragma unroll
  for (int j = tid; j < NFFT / 4; j += BLK) {
    const int i0 = j << 2;
    float2 x0 = Z[swz(i0)], x1 = Z[swz(i0 + 1)], x2 = Z[swz(i0 + 2)], x3 = Z[swz(i0 + 3)];
    float2 a = cadd(x0, x2), b = csub(x0, x2);
    float2 cc = cadd(x1, x3), d = csub(x1, x3);
    Z[swz(i0)]     = cadd(a, cc);
    Z[swz(i0 + 1)] = make_float2(b.x + d.y, b.y - d.x);
    Z[swz(i0 + 2)] = csub(a, cc);
    Z[swz(i0 + 3)] = make_float2(b.x - d.y, b.y + d.x);
  }
  __syncthreads();
}

// inverse: digit-reversed -> natural (unnormalized)
__device__ __forceinline__ void fft_inv(float2* Z, const float2* __restrict__ tw, int tid) {
#pragma unroll
  for (int qlog = 0; qlog <= 8; qlog += 4) {    // fused stage pairs (q, 4q)
    const int q = 1 << qlog, m = q << 2;
    const int tsA = NFFT >> (qlog + 2);
    const int tsB = NFFT >> (qlog + 4);
#pragma unroll
    for (int j = tid; j < NPAIR; j += BLK) {
      const int u = j & (q - 1);
      const int g = j >> qlog;
      const int base = (g << (qlog + 4)) + u;
      float2 e[4][4];
#pragma unroll
      for (int s = 0; s < 4; ++s)
#pragma unroll
        for (int t = 0; t < 4; ++t) e[s][t] = Z[swz(base + s * m + t * q)];
      // stage A: radix-4 DIT over t (span q), exponent u*tsA
      {
        float2 v1 = cconj(tw[u * tsA]);
        float2 v2 = cmul(v1, v1);
        float2 v3 = cmul(v2, v1);
#pragma unroll
        for (int s = 0; s < 4; ++s) {
          float2 t0 = e[s][0];
          float2 t1 = cmul(e[s][1], v1);
          float2 t2 = cmul(e[s][2], v2);
          float2 t3 = cmul(e[s][3], v3);
          float2 a = cadd(t0, t2), b = csub(t0, t2);
          float2 cc = cadd(t1, t3), d = csub(t1, t3);
          e[s][0] = cadd(a, cc);
          e[s][1] = make_float2(b.x - d.y, b.y + d.x);
          e[s][2] = csub(a, cc);
          e[s][3] = make_float2(b.x + d.y, b.y - d.x);
        }
      }
      // stage B: radix-4 DIT over s (span m), exponent (u+t*q)*tsB
#pragma unroll
      for (int t = 0; t < 4; ++t) {
        float2 w1 = cconj(tw[(u + t * q) * tsB]);
        float2 w2 = cmul(w1, w1);
        float2 w3 = cmul(w2, w1);
        float2 t0 = e[0][t];
        float2 t1 = cmul(e[1][t], w1);
        float2 t2 = cmul(e[2][t], w2);
        float2 t3 = cmul(e[3][t], w3);
        float2 a = cadd(t0, t2), b = csub(t0, t2);
        float2 cc = cadd(t1, t3), d = csub(t1, t3);
        e[0][t] = cadd(a, cc);
        e[1][t] = make_float2(b.x - d.y, b.y + d.x);
        e[2][t] = csub(a, cc);
        e[3][t] = make_float2(b.x + d.y, b.y - d.x);
      }
#pragma unroll
      for (int s = 0; s < 4; ++s)
#pragma unroll
        for (int t = 0; t < 4; ++t) Z[swz(base + s * m + t * q)] = e[s][t];
    }
    __syncthreads();
  }
  // final radix-4 stage (span 4096), exponent u
#pragma unroll
  for (int j = tid; j < NFFT / 4; j += BLK) {
    const int u = j;
    float2 w1 = cconj(tw[u]);
    float2 w2 = cmul(w1, w1);
    float2 w3 = cmul(w2, w1);
    float2 t0 = Z[swz(u)];
    float2 t1 = cmul(Z[swz(u + 4096)], w1);
    float2 t2 = cmul(Z[swz(u + 8192)], w2);
    float2 t3 = cmul(Z[swz(u + 12288)], w3);
    float2 a = cadd(t0, t2), b = csub(t0, t2);
    float2 cc = cadd(t1, t3), d = csub(t1, t3);
    Z[swz(u)]         = cadd(a, cc);
    Z[swz(u + 4096)]  = make_float2(b.x - d.y, b.y + d.x);
    Z[swz(u + 8192)]  = csub(a, cc);
    Z[swz(u + 12288)] = make_float2(b.x + d.y, b.y - d.x);
  }
  __syncthreads();
}

// ---------- conv: channel-pair x batch-pair per WG, K in registers ----------
__global__ __launch_bounds__(BLK, 2) void conv_kernel(
    const float* __restrict__ x,    // [B*C, L]
    const float* __restrict__ kf,   // [C, L]
    const float* __restrict__ bias, // [C]
    const float2* __restrict__ tw,  // [NFFT]
    float* __restrict__ out)        // [B*C, L]
{
  extern __shared__ float2 Z[];
  const int tid = threadIdx.x;
  const int cp = blockIdx.x % (CCH / 2);
  const int bp = blockIdx.x / (CCH / 2);
  const int c0 = cp * 2, c1 = c0 + 1;

  // ---- FFT of packed filter pair: Z = k_{c0} + i*k_{c1} ----
  {
    const float* kr0 = kf + (size_t)c0 * L_SEQ;
    const float* kr1 = kf + (size_t)c1 * L_SEQ;
#pragma unroll
    for (int i = tid; i < NFFT; i += BLK) {
      float re = 0.f, im = 0.f;
      if (i < L_SEQ) { re = kr0[i]; im = kr1[i]; }
      Z[swz(i)] = make_float2(re, im);
    }
    __syncthreads();
  }
  fft_fwd(Z, tw, tid);

  // ---- extract K0, K1 half-spectra into registers ----
  // thread holds bins f = tid + s*BLK; K?r[0] on tid 0 packs (DC, Nyquist)
  float2 K0r[16], K1r[16];
#pragma unroll
  for (int s = 0; s < 16; ++s) {
    const int f = tid + s * BLK;
    if (f == 0) {
      float2 z0 = Z[swz(0)];
      float2 zn = Z[swz(2)];          // rev4_14(8192) == 2
      K0r[0] = make_float2(z0.x, zn.x);
      K1r[0] = make_float2(z0.y, zn.y);
    } else {
      const int p = swz(rev4_14(f));
      const int qq = swz(rev4_14(NFFT - f));
      float2 zp = Z[p], zq = Z[qq];
      K0r[s] = make_float2(0.5f * (zp.x + zq.x), 0.5f * (zp.y - zq.y));
      K1r[s] = make_float2(0.5f * (zp.y + zq.y), -0.5f * (zp.x - zq.x));
    }
  }
  __syncthreads();

  const float bias0 = bias[c0], bias1 = bias[c1];
  const float scale = 1.0f / (float)NFFT;

  // ---- two batch rows per channel pair ----
#pragma unroll 1
  for (int bb = 0; bb < 2; ++bb) {
    const int b = bp * 2 + bb;
    const float* xr0 = x + (size_t)(b * CCH + c0) * L_SEQ;
    const float* xr1 = x + (size_t)(b * CCH + c1) * L_SEQ;
    float* o0 = out + (size_t)(b * CCH + c0) * L_SEQ;
    float* o1 = out + (size_t)(b * CCH + c1) * L_SEQ;

#pragma unroll
    for (int i = tid; i < NFFT; i += BLK) {
      float re = 0.f, im = 0.f;
      if (i < L_SEQ) { re = xr0[i]; im = xr1[i]; }
      Z[swz(i)] = make_float2(re, im);
    }
    __syncthreads();
    fft_fwd(Z, tw, tid);

    // unpack X0,X1; Y = X*K*scale; repack Y0 + i*Y1 (Hermitian)
#pragma unroll
    for (int s = 0; s < 16; ++s) {
      const int f = tid + s * BLK;
      if (f == 0) {
        const int p0 = swz(0), pn = swz(2);
        float2 z0 = Z[p0], zn = Z[pn];
        Z[p0] = make_float2(z0.x * K0r[0].x * scale, z0.y * K1r[0].x * scale);
        Z[pn] = make_float2(zn.x * K0r[0].y * scale, zn.y * K1r[0].y * scale);
      } else {
        const int p = swz(rev4_14(f));
        const int qq = swz(rev4_14(NFFT - f));
        float2 zp = Z[p], zq = Z[qq];
        float2 X0 = make_float2(0.5f * (zp.x + zq.x), 0.5f * (zp.y - zq.y));
        float2 X1 = make_float2(0.5f * (zp.y + zq.y), -0.5f * (zp.x - zq.x));
        float2 Y0 = cmul(X0, K0r[s]);
        float2 Y1 = cmul(X1, K1r[s]);
        Y0.x *= scale; Y0.y *= scale; Y1.x *= scale; Y1.y *= scale;
        Z[p]  = make_float2(Y0.x - Y1.y, Y0.y + Y1.x);
        Z[qq] = make_float2(Y0.x + Y1.y, Y1.x - Y0.y);
      }
    }
    __syncthreads();
    fft_inv(Z, tw, tid);

    // epilogue: y0 = Re, y1 = Im, + x*bias
#pragma unroll
    for (int i = tid; i < L_SEQ; i += BLK) {
      float2 zz = Z[swz(i)];
      o0[i] = zz.x + xr0[i] * bias0;
      o1[i] = zz.y + xr1[i] * bias1;
    }
    __syncthreads();
  }
}

extern "C" void kernel_launch(void* const* d_in, const int* in_sizes, int n_in,
                              void* d_out, int out_size, void* d_ws, size_t ws_size,
                              hipStream_t stream) {
  const float* x      = (const float*)d_in[0];
  const float* bias   = (const float*)d_in[1];
  const float* z      = (const float*)d_in[2];
  const float* t      = (const float*)d_in[3];
  const float* deltas = (const float*)d_in[4];
  const float* freq   = (const float*)d_in[5];
  const float* w0     = (const float*)d_in[6];
  const float* b0     = (const float*)d_in[7];
  const float* w1     = (const float*)d_in[8];
  const float* b1     = (const float*)d_in[9];
  const float* w2     = (const float*)d_in[10];
  const float* b2     = (const float*)d_in[11];
  const float* wout   = (const float*)d_in[12];
  float* out = (float*)d_out;

  // workspace: [twiddles 128KB][h 2MB][k 24MB]
  float2* tw = (float2*)d_ws;
  float* h     = (float*)((char*)d_ws + (size_t)NFFT * sizeof(float2));
  float* kfilt = (float*)((char*)d_ws + (size_t)NFFT * sizeof(float2) +
                          (size_t)ODIM * L_SEQ * sizeof(float));

  twiddle_kernel<<<NFFT / 256, 256, 0, stream>>>(tw);
  mlp_kernel<<<L_SEQ / 64, 64, 0, stream>>>(z, freq, w0, b0, w1, b1, w2, b2, h);
  kout_kernel<<<(L_SEQ / KT_L) * (CCH / KT_C), KT_L, 0, stream>>>(h, wout, t, deltas, kfilt);

  hipFuncSetAttribute(reinterpret_cast<const void*>(conv_kernel),
                      hipFuncAttributeMaxDynamicSharedMemorySize,
                      NFFT * sizeof(float2));
  conv_kernel<<<(BB / 2) * (CCH / 2), BLK, NFFT * sizeof(float2), stream>>>(
      x, kfilt, bias, tw, out);
}

// Round 3
// 396.258 us; speedup vs baseline: 2.7592x; 2.7592x over previous
//
#include <hip/hip_runtime.h>
#include <math.h>

#define L_SEQ 8192
#define NFFT  16384
#define CCH   768
#define BB    4
#define EDIM  33
#define ODIM  64
#define BLK   512
#define NPAIR (NFFT / 16)

// ---------- complex helpers ----------
__device__ __forceinline__ float2 cadd(float2 a, float2 b) { return make_float2(a.x + b.x, a.y + b.y); }
__device__ __forceinline__ float2 csub(float2 a, float2 b) { return make_float2(a.x - b.x, a.y - b.y); }
__device__ __forceinline__ float2 cmul(float2 a, float2 b) {
  return make_float2(fmaf(a.x, b.x, -a.y * b.y), fmaf(a.x, b.y, a.y * b.x));
}
__device__ __forceinline__ float2 cconj(float2 a) { return make_float2(a.x, -a.y); }

// LDS swizzle: fold bits 4-11 into the bank nibble. Bijective (modified bits
// 0-3 don't feed the XOR sources). Fixes the 32-way conflict in the
// digit-reversed spectral-multiply pass (partner indices differ only in
// bits>=8) while keeping FFT-round passes at worst 4-way.
__device__ __forceinline__ int swz(int i) { return i ^ ((i >> 4) & 15) ^ ((i >> 8) & 15); }

// reverse 7 base-4 digits of a 14-bit index
__device__ __forceinline__ int rev4_14(int v) {
  int r = 0;
#pragma unroll
  for (int i = 0; i < 7; ++i) { r = (r << 2) | (v & 3); v >>= 2; }
  return r;
}

// ---------- twiddle table W_N^r = exp(-2*pi*i*r/N) ----------
__global__ void twiddle_kernel(float2* __restrict__ tw) {
  int r = blockIdx.x * blockDim.x + threadIdx.x;
  if (r < NFFT) {
    float th = (float)(6.283185307179586476925286766559 / (double)NFFT) * (float)r;
    float s, c;
    sincosf(th, &s, &c);
    tw[r] = make_float2(c, -s);
  }
}

// ---------- MLP: h[o][l] = 3x(Dense+Sin) of z[l] ----------
__global__ __launch_bounds__(256) void mlp_kernel(
    const float* __restrict__ z,      // [L, 33]
    const float* __restrict__ freq,   // [64]
    const float* __restrict__ w0, const float* __restrict__ b0,
    const float* __restrict__ w1, const float* __restrict__ b1,
    const float* __restrict__ w2, const float* __restrict__ b2,
    float* __restrict__ h)            // [64][L]
{
  int l = blockIdx.x * 256 + threadIdx.x;
  float zb[EDIM];
#pragma unroll
  for (int e = 0; e < EDIM; ++e) zb[e] = z[l * EDIM + e];

  float ha[ODIM], hb[ODIM];
#pragma unroll
  for (int o = 0; o < ODIM; ++o) {
    float acc = b0[o];
#pragma unroll
    for (int e = 0; e < EDIM; ++e) acc = fmaf(zb[e], w0[e * ODIM + o], acc);
    ha[o] = sinf(freq[o] * acc);
  }
#pragma unroll
  for (int o = 0; o < ODIM; ++o) {
    float acc = b1[o];
#pragma unroll
    for (int i = 0; i < ODIM; ++i) acc = fmaf(ha[i], w1[i * ODIM + o], acc);
    hb[o] = sinf(freq[o] * acc);
  }
#pragma unroll
  for (int o = 0; o < ODIM; ++o) {
    float acc = b2[o];
#pragma unroll
    for (int i = 0; i < ODIM; ++i) acc = fmaf(hb[i], w2[i * ODIM + o], acc);
    h[o * L_SEQ + l] = sinf(freq[o] * acc);
  }
}

// ---------- k[c][l] = (h . wout[:,c]) * exp(-t[l]*|deltas[c]|) ----------
#define KT_L 128
#define KT_C 64
__global__ __launch_bounds__(KT_L) void kout_kernel(
    const float* __restrict__ h,      // [64][L]
    const float* __restrict__ wout,   // [64][768]
    const float* __restrict__ t,      // [L]
    const float* __restrict__ deltas, // [768]
    float* __restrict__ k)            // [768][L]
{
  __shared__ float hT[ODIM][KT_L];
  __shared__ float wT[ODIM][KT_C];
  const int lb = blockIdx.x % (L_SEQ / KT_L);
  const int cb = blockIdx.x / (L_SEQ / KT_L);
  const int l0 = lb * KT_L, c0 = cb * KT_C;
  const int tid = threadIdx.x;
  for (int i = tid; i < ODIM * KT_L; i += KT_L) {
    int o = i / KT_L, ll = i % KT_L;
    hT[o][ll] = h[o * L_SEQ + l0 + ll];
  }
  for (int i = tid; i < ODIM * KT_C; i += KT_L) {
    int o = i / KT_C, cc = i % KT_C;
    wT[o][cc] = wout[o * CCH + c0 + cc];
  }
  __syncthreads();
  float hv[ODIM];
#pragma unroll
  for (int o = 0; o < ODIM; ++o) hv[o] = hT[o][tid];
  const float tl = t[l0 + tid];
  for (int c = 0; c < KT_C; ++c) {
    float acc = 0.f;
#pragma unroll
    for (int o = 0; o < ODIM; ++o) acc = fmaf(hv[o], wT[o][c], acc);
    float mod = expf(-tl * fabsf(deltas[c0 + c]));
    k[(size_t)(c0 + c) * L_SEQ + l0 + tid] = acc * mod;
  }
}

// ---------- in-LDS FFT, radix-4 DIF with fused radix-16 rounds ----------
// forward: natural -> base4-digit-reversed
__device__ __forceinline__ void fft_fwd(float2* Z, const float2* __restrict__ tw, int tid) {
#pragma unroll
  for (int mlog = 12; mlog >= 4; mlog -= 4) {   // fused stage pairs (m, m/4)
    const int m = 1 << mlog, q = m >> 2;
    const int tsA = NFFT >> (mlog + 2);
    const int tsB = NFFT >> mlog;
#pragma unroll
    for (int j = tid; j < NPAIR; j += BLK) {
      const int u = j & (q - 1);
      const int g = j >> (mlog - 2);
      const int base = (g << (mlog + 2)) + u;
      float2 e[4][4];
#pragma unroll
      for (int s = 0; s < 4; ++s)
#pragma unroll
        for (int t = 0; t < 4; ++t) e[s][t] = Z[swz(base + s * m + t * q)];
#pragma unroll
      for (int t = 0; t < 4; ++t) {
        float2 a = cadd(e[0][t], e[2][t]), b = csub(e[0][t], e[2][t]);
        float2 cc = cadd(e[1][t], e[3][t]), d = csub(e[1][t], e[3][t]);
        float2 w1 = tw[(u + t * q) * tsA];
        float2 w2 = cmul(w1, w1);
        float2 w3 = cmul(w2, w1);
        e[0][t] = cadd(a, cc);
        e[1][t] = cmul(make_float2(b.x + d.y, b.y - d.x), w1);
        e[2][t] = cmul(csub(a, cc), w2);
        e[3][t] = cmul(make_float2(b.x - d.y, b.y + d.x), w3);
      }
      {
        float2 w1 = tw[u * tsB];
        float2 w2 = cmul(w1, w1);
        float2 w3 = cmul(w2, w1);
#pragma unroll
        for (int s = 0; s < 4; ++s) {
          float2 a = cadd(e[s][0], e[s][2]), b = csub(e[s][0], e[s][2]);
          float2 cc = cadd(e[s][1], e[s][3]), d = csub(e[s][1], e[s][3]);
          e[s][0] = cadd(a, cc);
          e[s][1] = cmul(make_float2(b.x + d.y, b.y - d.x), w1);
          e[s][2] = cmul(csub(a, cc), w2);
          e[s][3] = cmul(make_float2(b.x - d.y, b.y + d.x), w3);
        }
      }
#pragma unroll
      for (int s = 0; s < 4; ++s)
#pragma unroll
        for (int t = 0; t < 4; ++t) Z[swz(base + s * m + t * q)] = e[s][t];
    }
    __syncthreads();
  }
  // final radix-4 stage (span 1, twiddle-free)
#pragma unroll
  for (int j = tid; j < NFFT / 4; j += BLK) {
    const int i0 = j << 2;
    float2 x0 = Z[swz(i0)], x1 = Z[swz(i0 + 1)], x2 = Z[swz(i0 + 2)], x3 = Z[swz(i0 + 3)];
    float2 a = cadd(x0, x2), b = csub(x0, x2);
    float2 cc = cadd(x1, x3), d = csub(x1, x3);
    Z[swz(i0)]     = cadd(a, cc);
    Z[swz(i0 + 1)] = make_float2(b.x + d.y, b.y - d.x);
    Z[swz(i0 + 2)] = csub(a, cc);
    Z[swz(i0 + 3)] = make_float2(b.x - d.y, b.y + d.x);
  }
  __syncthreads();
}

// inverse: digit-reversed -> natural (unnormalized)
__device__ __forceinline__ void fft_inv(float2* Z, const float2* __restrict__ tw, int tid) {
#pragma unroll
  for (int qlog = 0; qlog <= 8; qlog += 4) {    // fused stage pairs (q, 4q)
    const int q = 1 << qlog, m = q << 2;
    const int tsA = NFFT >> (qlog + 2);
    const int tsB = NFFT >> (qlog + 4);
#pragma unroll
    for (int j = tid; j < NPAIR; j += BLK) {
      const int u = j & (q - 1);
      const int g = j >> qlog;
      const int base = (g << (qlog + 4)) + u;
      float2 e[4][4];
#pragma unroll
      for (int s = 0; s < 4; ++s)
#pragma unroll
        for (int t = 0; t < 4; ++t) e[s][t] = Z[swz(base + s * m + t * q)];
      {
        float2 v1 = cconj(tw[u * tsA]);
        float2 v2 = cmul(v1, v1);
        float2 v3 = cmul(v2, v1);
#pragma unroll
        for (int s = 0; s < 4; ++s) {
          float2 t0 = e[s][0];
          float2 t1 = cmul(e[s][1], v1);
          float2 t2 = cmul(e[s][2], v2);
          float2 t3 = cmul(e[s][3], v3);
          float2 a = cadd(t0, t2), b = csub(t0, t2);
          float2 cc = cadd(t1, t3), d = csub(t1, t3);
          e[s][0] = cadd(a, cc);
          e[s][1] = make_float2(b.x - d.y, b.y + d.x);
          e[s][2] = csub(a, cc);
          e[s][3] = make_float2(b.x + d.y, b.y - d.x);
        }
      }
#pragma unroll
      for (int t = 0; t < 4; ++t) {
        float2 w1 = cconj(tw[(u + t * q) * tsB]);
        float2 w2 = cmul(w1, w1);
        float2 w3 = cmul(w2, w1);
        float2 t0 = e[0][t];
        float2 t1 = cmul(e[1][t], w1);
        float2 t2 = cmul(e[2][t], w2);
        float2 t3 = cmul(e[3][t], w3);
        float2 a = cadd(t0, t2), b = csub(t0, t2);
        float2 cc = cadd(t1, t3), d = csub(t1, t3);
        e[0][t] = cadd(a, cc);
        e[1][t] = make_float2(b.x - d.y, b.y + d.x);
        e[2][t] = csub(a, cc);
        e[3][t] = make_float2(b.x + d.y, b.y - d.x);
      }
#pragma unroll
      for (int s = 0; s < 4; ++s)
#pragma unroll
        for (int t = 0; t < 4; ++t) Z[swz(base + s * m + t * q)] = e[s][t];
    }
    __syncthreads();
  }
  // final radix-4 stage (span 4096), exponent u
#pragma unroll
  for (int j = tid; j < NFFT / 4; j += BLK) {
    const int u = j;
    float2 w1 = cconj(tw[u]);
    float2 w2 = cmul(w1, w1);
    float2 w3 = cmul(w2, w1);
    float2 t0 = Z[swz(u)];
    float2 t1 = cmul(Z[swz(u + 4096)], w1);
    float2 t2 = cmul(Z[swz(u + 8192)], w2);
    float2 t3 = cmul(Z[swz(u + 12288)], w3);
    float2 a = cadd(t0, t2), b = csub(t0, t2);
    float2 cc = cadd(t1, t3), d = csub(t1, t3);
    Z[swz(u)]         = cadd(a, cc);
    Z[swz(u + 4096)]  = make_float2(b.x - d.y, b.y + d.x);
    Z[swz(u + 8192)]  = csub(a, cc);
    Z[swz(u + 12288)] = make_float2(b.x + d.y, b.y - d.x);
  }
  __syncthreads();
}

// ---------- kfft: FFT channel pair, store both half-spectra to global ----------
// Kf[c][f], f in [0, 8192): bins 1..8191; f==0 packs (DC, Nyquist) (both real).
__global__ __launch_bounds__(BLK) void kfft_kernel(
    const float* __restrict__ kf,   // [C, L]
    const float2* __restrict__ tw,
    float2* __restrict__ Kf)        // [C, NFFT/2]
{
  extern __shared__ float2 Z[];
  const int cp = blockIdx.x;
  const int c0 = 2 * cp, c1 = c0 + 1;
  const int tid = threadIdx.x;
  const float* kr0 = kf + (size_t)c0 * L_SEQ;
  const float* kr1 = kf + (size_t)c1 * L_SEQ;
#pragma unroll
  for (int i = tid; i < NFFT; i += BLK) {
    float re = 0.f, im = 0.f;
    if (i < L_SEQ) { re = kr0[i]; im = kr1[i]; }
    Z[swz(i)] = make_float2(re, im);
  }
  __syncthreads();
  fft_fwd(Z, tw, tid);

  float2* K0 = Kf + (size_t)c0 * (NFFT / 2);
  float2* K1 = Kf + (size_t)c1 * (NFFT / 2);
#pragma unroll
  for (int s = 0; s < 16; ++s) {
    const int f = tid + s * BLK;
    if (f == 0) {
      float2 z0 = Z[swz(0)];
      float2 zn = Z[swz(2)];          // rev4_14(8192) == 2
      K0[0] = make_float2(z0.x, zn.x);
      K1[0] = make_float2(z0.y, zn.y);
    } else {
      const int p = swz(rev4_14(f));
      const int qq = swz(rev4_14(NFFT - f));
      float2 zp = Z[p], zq = Z[qq];
      K0[f] = make_float2(0.5f * (zp.x + zq.x), 0.5f * (zp.y - zq.y));
      K1[f] = make_float2(0.5f * (zp.y + zq.y), -0.5f * (zp.x - zq.x));
    }
  }
}

// ---------- conv: one (batch, channel-pair) per WG, K streamed from global ----------
__global__ __launch_bounds__(BLK) void conv_kernel(
    const float* __restrict__ x,    // [B*C, L]
    const float2* __restrict__ Kf,  // [C, NFFT/2]
    const float* __restrict__ bias, // [C]
    const float2* __restrict__ tw,
    float* __restrict__ out)        // [B*C, L]
{
  extern __shared__ float2 Z[];
  const int tid = threadIdx.x;
  const int cp = blockIdx.x % (CCH / 2);
  const int b  = blockIdx.x / (CCH / 2);
  const int c0 = 2 * cp, c1 = c0 + 1;
  const float* xr0 = x + (size_t)(b * CCH + c0) * L_SEQ;
  const float* xr1 = x + (size_t)(b * CCH + c1) * L_SEQ;

#pragma unroll
  for (int i = tid; i < NFFT; i += BLK) {
    float re = 0.f, im = 0.f;
    if (i < L_SEQ) { re = xr0[i]; im = xr1[i]; }
    Z[swz(i)] = make_float2(re, im);
  }
  __syncthreads();
  fft_fwd(Z, tw, tid);

  const float2* K0 = Kf + (size_t)c0 * (NFFT / 2);
  const float2* K1 = Kf + (size_t)c1 * (NFFT / 2);
  const float scale = 1.0f / (float)NFFT;
#pragma unroll
  for (int s = 0; s < 16; ++s) {
    const int f = tid + s * BLK;
    float2 k0 = K0[f];
    float2 k1 = K1[f];
    if (f == 0) {
      const int p0 = swz(0), pn = swz(2);
      float2 z0 = Z[p0], zn = Z[pn];
      Z[p0] = make_float2(z0.x * k0.x * scale, z0.y * k1.x * scale);
      Z[pn] = make_float2(zn.x * k0.y * scale, zn.y * k1.y * scale);
    } else {
      const int p = swz(rev4_14(f));
      const int qq = swz(rev4_14(NFFT - f));
      float2 zp = Z[p], zq = Z[qq];
      float2 X0 = make_float2(0.5f * (zp.x + zq.x), 0.5f * (zp.y - zq.y));
      float2 X1 = make_float2(0.5f * (zp.y + zq.y), -0.5f * (zp.x - zq.x));
      float2 Y0 = cmul(X0, k0);
      float2 Y1 = cmul(X1, k1);
      Y0.x *= scale; Y0.y *= scale; Y1.x *= scale; Y1.y *= scale;
      Z[p]  = make_float2(Y0.x - Y1.y, Y0.y + Y1.x);
      Z[qq] = make_float2(Y0.x + Y1.y, Y1.x - Y0.y);
    }
  }
  __syncthreads();
  fft_inv(Z, tw, tid);

  const float b0v = bias[c0], b1v = bias[c1];
  float* o0 = out + (size_t)(b * CCH + c0) * L_SEQ;
  float* o1 = out + (size_t)(b * CCH + c1) * L_SEQ;
#pragma unroll
  for (int i = tid; i < L_SEQ; i += BLK) {
    float2 zz = Z[swz(i)];
    o0[i] = zz.x + xr0[i] * b0v;
    o1[i] = zz.y + xr1[i] * b1v;
  }
}

// ---------- fallback (small ws): round-1 style, x and k packed in one FFT ----------
__global__ __launch_bounds__(BLK) void conv_fb_kernel(
    const float* __restrict__ x,    // [B*C, L]
    const float* __restrict__ kf,   // [C, L]
    const float* __restrict__ bias, // [C]
    const float2* __restrict__ tw,
    float* __restrict__ out)        // [B*C, L]
{
  extern __shared__ float2 Z[];
  const int wg = blockIdx.x;
  const int c = wg % CCH;
  const int tid = threadIdx.x;
  const float* xr = x + (size_t)wg * L_SEQ;
  const float* kr = kf + (size_t)c * L_SEQ;

#pragma unroll
  for (int i = tid; i < NFFT; i += BLK) {
    float re = 0.f, im = 0.f;
    if (i < L_SEQ) { re = xr[i]; im = kr[i]; }
    Z[swz(i)] = make_float2(re, im);
  }
  __syncthreads();
  fft_fwd(Z, tw, tid);

  const float scale = 1.0f / (float)NFFT;
#pragma unroll
  for (int s = 0; s < 16; ++s) {
    const int f = tid + s * BLK;
    if (f == 0) {
      const int p0 = swz(0), pn = swz(2);
      float2 z0 = Z[p0], zn = Z[pn];
      Z[p0] = make_float2(z0.x * z0.y * scale, 0.f);
      Z[pn] = make_float2(zn.x * zn.y * scale, 0.f);
    } else {
      const int p = swz(rev4_14(f));
      const int qq = swz(rev4_14(NFFT - f));
      float2 zp = Z[p], zq = Z[qq];
      float2 X = make_float2(0.5f * (zp.x + zq.x), 0.5f * (zp.y - zq.y));
      float2 K = make_float2(0.5f * (zp.y + zq.y), -0.5f * (zp.x - zq.x));
      float2 Y = cmul(X, K);
      Y.x *= scale; Y.y *= scale;
      Z[p]  = Y;
      Z[qq] = make_float2(Y.x, -Y.y);
    }
  }
  __syncthreads();
  fft_inv(Z, tw, tid);

  const float bc = bias[c];
#pragma unroll
  for (int l = tid; l < L_SEQ; l += BLK) {
    out[(size_t)wg * L_SEQ + l] = Z[swz(l)].x + xr[l] * bc;
  }
}

extern "C" void kernel_launch(void* const* d_in, const int* in_sizes, int n_in,
                              void* d_out, int out_size, void* d_ws, size_t ws_size,
                              hipStream_t stream) {
  const float* x      = (const float*)d_in[0];
  const float* bias   = (const float*)d_in[1];
  const float* z      = (const float*)d_in[2];
  const float* t      = (const float*)d_in[3];
  const float* deltas = (const float*)d_in[4];
  const float* freq   = (const float*)d_in[5];
  const float* w0     = (const float*)d_in[6];
  const float* b0     = (const float*)d_in[7];
  const float* w1     = (const float*)d_in[8];
  const float* b1     = (const float*)d_in[9];
  const float* w2     = (const float*)d_in[10];
  const float* b2     = (const float*)d_in[11];
  const float* wout   = (const float*)d_in[12];
  float* out = (float*)d_out;

  // workspace layout: [tw 128KB][h 2MB][kfilt 24MB][Kf 48MB]
  const size_t tw_b    = (size_t)NFFT * sizeof(float2);
  const size_t h_b     = (size_t)ODIM * L_SEQ * sizeof(float);
  const size_t kfilt_b = (size_t)CCH * L_SEQ * sizeof(float);
  const size_t Kf_b    = (size_t)CCH * (NFFT / 2) * sizeof(float2);

  float2* tw    = (float2*)d_ws;
  float*  h     = (float*)((char*)d_ws + tw_b);
  float*  kfilt = (float*)((char*)d_ws + tw_b + h_b);
  float2* Kf    = (float2*)((char*)d_ws + tw_b + h_b + kfilt_b);
  const bool big_ws = ws_size >= tw_b + h_b + kfilt_b + Kf_b;

  twiddle_kernel<<<NFFT / 256, 256, 0, stream>>>(tw);
  mlp_kernel<<<L_SEQ / 256, 256, 0, stream>>>(z, freq, w0, b0, w1, b1, w2, b2, h);
  kout_kernel<<<(L_SEQ / KT_L) * (CCH / KT_C), KT_L, 0, stream>>>(h, wout, t, deltas, kfilt);

  const size_t lds = (size_t)NFFT * sizeof(float2);
  if (big_ws) {
    hipFuncSetAttribute(reinterpret_cast<const void*>(kfft_kernel),
                        hipFuncAttributeMaxDynamicSharedMemorySize, lds);
    hipFuncSetAttribute(reinterpret_cast<const void*>(conv_kernel),
                        hipFuncAttributeMaxDynamicSharedMemorySize, lds);
    kfft_kernel<<<CCH / 2, BLK, lds, stream>>>(kfilt, tw, Kf);
    conv_kernel<<<BB * (CCH / 2), BLK, lds, stream>>>(x, Kf, bias, tw, out);
  } else {
    hipFuncSetAttribute(reinterpret_cast<const void*>(conv_fb_kernel),
                        hipFuncAttributeMaxDynamicSharedMemorySize, lds);
    conv_fb_kernel<<<BB * CCH, BLK, lds, stream>>>(x, kfilt, bias, tw, out);
  }
}

// Round 4
// 351.696 us; speedup vs baseline: 3.1088x; 1.1267x over previous
//
#include <hip/hip_runtime.h>
#include <math.h>

#define L_SEQ 8192
#define NFFT  16384     // conv length
#define N2    8192      // packed complex FFT length
#define N4    4096      // half (radix-2 block) length
#define CCH   768
#define BB    4
#define EDIM  33
#define ODIM  64
#define BLK   512

// ---------- complex helpers ----------
__device__ __forceinline__ float2 cadd(float2 a, float2 b) { return make_float2(a.x + b.x, a.y + b.y); }
__device__ __forceinline__ float2 csub(float2 a, float2 b) { return make_float2(a.x - b.x, a.y - b.y); }
__device__ __forceinline__ float2 cmul(float2 a, float2 b) {
  return make_float2(fmaf(a.x, b.x, -a.y * b.y), fmaf(a.x, b.y, a.y * b.x));
}
__device__ __forceinline__ float2 cconj(float2 a) { return make_float2(a.x, -a.y); }

// LDS swizzle: fold bits 4-11 into the bank nibble (bijective; upper bits unchanged).
__device__ __forceinline__ int swz(int i) { return i ^ ((i >> 4) & 15) ^ ((i >> 8) & 15); }

// reverse 6 base-4 digits of a 12-bit index
__device__ __forceinline__ int rev4_12(int v) {
  int r = 0;
#pragma unroll
  for (int i = 0; i < 6; ++i) { r = (r << 2) | (v & 3); v >>= 2; }
  return r;
}
// bin f (0..8191) of the packed FFT -> LDS position after DIF (r2 first, then 3 fused r16)
__device__ __forceinline__ int pos8(int f) { return ((f & 1) << 12) | rev4_12(f >> 1); }

// ---------- twiddle table W_16384^r ----------
__global__ void twiddle_kernel(float2* __restrict__ tw) {
  int r = blockIdx.x * blockDim.x + threadIdx.x;
  if (r < NFFT) {
    float th = (float)(6.283185307179586476925286766559 / (double)NFFT) * (float)r;
    float s, c;
    sincosf(th, &s, &c);
    tw[r] = make_float2(c, -s);
  }
}

// ---------- MLP: h[o][l] ----------
__global__ __launch_bounds__(64) void mlp_kernel(
    const float* __restrict__ z, const float* __restrict__ freq,
    const float* __restrict__ w0, const float* __restrict__ b0,
    const float* __restrict__ w1, const float* __restrict__ b1,
    const float* __restrict__ w2, const float* __restrict__ b2,
    float* __restrict__ h)            // [64][L]
{
  int l = blockIdx.x * 64 + threadIdx.x;
  float zb[EDIM];
#pragma unroll
  for (int e = 0; e < EDIM; ++e) zb[e] = z[l * EDIM + e];
  float ha[ODIM], hb[ODIM];
#pragma unroll
  for (int o = 0; o < ODIM; ++o) {
    float acc = b0[o];
#pragma unroll
    for (int e = 0; e < EDIM; ++e) acc = fmaf(zb[e], w0[e * ODIM + o], acc);
    ha[o] = sinf(freq[o] * acc);
  }
#pragma unroll
  for (int o = 0; o < ODIM; ++o) {
    float acc = b1[o];
#pragma unroll
    for (int i = 0; i < ODIM; ++i) acc = fmaf(ha[i], w1[i * ODIM + o], acc);
    hb[o] = sinf(freq[o] * acc);
  }
#pragma unroll
  for (int o = 0; o < ODIM; ++o) {
    float acc = b2[o];
#pragma unroll
    for (int i = 0; i < ODIM; ++i) acc = fmaf(hb[i], w2[i * ODIM + o], acc);
    h[o * L_SEQ + l] = sinf(freq[o] * acc);
  }
}

// ---------- k[c][l] = (h . wout[:,c]) * exp(-t[l]*|deltas[c]|) ----------
#define KT_L 128
#define KT_C 64
__global__ __launch_bounds__(KT_L) void kout_kernel(
    const float* __restrict__ h, const float* __restrict__ wout,
    const float* __restrict__ t, const float* __restrict__ deltas,
    float* __restrict__ k)            // [768][L]
{
  __shared__ float hT[ODIM][KT_L];
  __shared__ float wT[ODIM][KT_C];
  const int lb = blockIdx.x % (L_SEQ / KT_L);
  const int cb = blockIdx.x / (L_SEQ / KT_L);
  const int l0 = lb * KT_L, c0 = cb * KT_C;
  const int tid = threadIdx.x;
  for (int i = tid; i < ODIM * KT_L; i += KT_L) {
    int o = i / KT_L, ll = i % KT_L;
    hT[o][ll] = h[o * L_SEQ + l0 + ll];
  }
  for (int i = tid; i < ODIM * KT_C; i += KT_L) {
    int o = i / KT_C, cc = i % KT_C;
    wT[o][cc] = wout[o * CCH + c0 + cc];
  }
  __syncthreads();
  float hv[ODIM];
#pragma unroll
  for (int o = 0; o < ODIM; ++o) hv[o] = hT[o][tid];
  const float tl = t[l0 + tid];
  for (int c = 0; c < KT_C; ++c) {
    float acc = 0.f;
#pragma unroll
    for (int o = 0; o < ODIM; ++o) acc = fmaf(hv[o], wT[o][c], acc);
    float mod = expf(-tl * fabsf(deltas[c0 + c]));
    k[(size_t)(c0 + c) * L_SEQ + l0 + tid] = acc * mod;
  }
}

// ---------- 3 fused radix-16 DIF rounds over two independent 4096 halves ----------
// tw exponents are in W_16384 units (x4 relative to W_4096).
__device__ __forceinline__ void fft4k2_fwd(float2* Z, const float2* __restrict__ tw, int tid) {
#pragma unroll
  for (int mlog = 10; mlog >= 2; mlog -= 4) {   // fused stage pairs (m, m/4): m=1024,64,4
    const int m = 1 << mlog, q = m >> 2;
    const int tsA = N4 >> mlog;                  // 4096/m
    const int tsB = NFFT >> mlog;                // 16384/m
    const int h = tid >> 8, jp = tid & 255;
    const int u = jp & (q - 1);
    const int g = jp >> (mlog - 2);
    const int base = (h << 12) + (g << (mlog + 2)) + u;
    float2 e[4][4];
#pragma unroll
    for (int s = 0; s < 4; ++s)
#pragma unroll
      for (int t = 0; t < 4; ++t) e[s][t] = Z[swz(base + s * m + t * q)];
#pragma unroll
    for (int t = 0; t < 4; ++t) {              // stage A: span m
      float2 a = cadd(e[0][t], e[2][t]), b = csub(e[0][t], e[2][t]);
      float2 cc = cadd(e[1][t], e[3][t]), d = csub(e[1][t], e[3][t]);
      float2 w1 = tw[(u + t * q) * tsA];
      float2 w2 = cmul(w1, w1);
      float2 w3 = cmul(w2, w1);
      e[0][t] = cadd(a, cc);
      e[1][t] = cmul(make_float2(b.x + d.y, b.y - d.x), w1);
      e[2][t] = cmul(csub(a, cc), w2);
      e[3][t] = cmul(make_float2(b.x - d.y, b.y + d.x), w3);
    }
    {                                           // stage B: span q
      float2 w1 = tw[u * tsB];
      float2 w2 = cmul(w1, w1);
      float2 w3 = cmul(w2, w1);
#pragma unroll
      for (int s = 0; s < 4; ++s) {
        float2 a = cadd(e[s][0], e[s][2]), b = csub(e[s][0], e[s][2]);
        float2 cc = cadd(e[s][1], e[s][3]), d = csub(e[s][1], e[s][3]);
        e[s][0] = cadd(a, cc);
        e[s][1] = cmul(make_float2(b.x + d.y, b.y - d.x), w1);
        e[s][2] = cmul(csub(a, cc), w2);
        e[s][3] = cmul(make_float2(b.x - d.y, b.y + d.x), w3);
      }
    }
#pragma unroll
    for (int s = 0; s < 4; ++s)
#pragma unroll
      for (int t = 0; t < 4; ++t) Z[swz(base + s * m + t * q)] = e[s][t];
    __syncthreads();
  }
}

// ---------- 3 fused radix-16 DIT rounds (inverse, conj twiddles) ----------
__device__ __forceinline__ void fft4k2_inv(float2* Z, const float2* __restrict__ tw, int tid) {
#pragma unroll
  for (int qlog = 0; qlog <= 8; qlog += 4) {    // fused stage pairs (q, 4q): q=1,16,256
    const int q = 1 << qlog, m = q << 2;
    const int tsA = N4 >> qlog;                  // 4096/q
    const int tsB = (N4 >> qlog) >> 2;           // 1024/q
    const int h = tid >> 8, jp = tid & 255;
    const int u = jp & (q - 1);
    const int g = jp >> qlog;
    const int base = (h << 12) + (g << (qlog + 4)) + u;
    float2 e[4][4];
#pragma unroll
    for (int s = 0; s < 4; ++s)
#pragma unroll
      for (int t = 0; t < 4; ++t) e[s][t] = Z[swz(base + s * m + t * q)];
    {                                           // stage A: span q (over t)
      float2 v1 = cconj(tw[u * tsA]);
      float2 v2 = cmul(v1, v1);
      float2 v3 = cmul(v2, v1);
#pragma unroll
      for (int s = 0; s < 4; ++s) {
        float2 t0 = e[s][0];
        float2 t1 = cmul(e[s][1], v1);
        float2 t2 = cmul(e[s][2], v2);
        float2 t3 = cmul(e[s][3], v3);
        float2 a = cadd(t0, t2), b = csub(t0, t2);
        float2 cc = cadd(t1, t3), d = csub(t1, t3);
        e[s][0] = cadd(a, cc);
        e[s][1] = make_float2(b.x - d.y, b.y + d.x);
        e[s][2] = csub(a, cc);
        e[s][3] = make_float2(b.x + d.y, b.y - d.x);
      }
    }
#pragma unroll
    for (int t = 0; t < 4; ++t) {               // stage B: span m (over s)
      float2 w1 = cconj(tw[(u + t * q) * tsB]);
      float2 w2 = cmul(w1, w1);
      float2 w3 = cmul(w2, w1);
      float2 t0 = e[0][t];
      float2 t1 = cmul(e[1][t], w1);
      float2 t2 = cmul(e[2][t], w2);
      float2 t3 = cmul(e[3][t], w3);
      float2 a = cadd(t0, t2), b = csub(t0, t2);
      float2 cc = cadd(t1, t3), d = csub(t1, t3);
      e[0][t] = cadd(a, cc);
      e[1][t] = make_float2(b.x - d.y, b.y + d.x);
      e[2][t] = csub(a, cc);
      e[3][t] = make_float2(b.x + d.y, b.y - d.x);
    }
#pragma unroll
    for (int s = 0; s < 4; ++s)
#pragma unroll
      for (int t = 0; t < 4; ++t) Z[swz(base + s * m + t * q)] = e[s][t];
    __syncthreads();
  }
}

// ---------- kfft: one channel per WG; packed even/odd 8192-FFT; store K half-spectrum ----------
// Kf[c][0] = (K[0], K[16384/2]); Kf[c][f] = K[f] for f in [1, 8192).  (K = rfft16384(k))
__global__ __launch_bounds__(BLK) void kfft_kernel(
    const float* __restrict__ kf, const float2* __restrict__ tw,
    float2* __restrict__ Kf)
{
  extern __shared__ float2 Z[];
  const int c = blockIdx.x, tid = threadIdx.x;
  const float2* k2 = (const float2*)(kf + (size_t)c * L_SEQ);
  // load + fused radix-2 DIF (upper half of padded input is zero)
#pragma unroll
  for (int i = tid; i < N4; i += BLK) {
    float2 v = k2[i];
    Z[swz(i)] = v;
    Z[swz(i + N4)] = cmul(v, tw[2 * i]);
  }
  __syncthreads();
  fft4k2_fwd(Z, tw, tid);

  float2* Kc = Kf + (size_t)c * N2;
#pragma unroll
  for (int s2 = 0; s2 < 8; ++s2) {
    const int f = tid + s2 * BLK;
    if (f == 0) {
      float2 z0 = Z[swz(0)];
      Kc[0] = make_float2(z0.x + z0.y, z0.x - z0.y);   // (K[0], K[8192]) both real
      float2 z4 = Z[swz(2)];                            // pos8(4096)==2
      Kc[N4] = make_float2(z4.x, -z4.y);                // K[4096] = conj(Z[4096])
    } else {
      float2 zf = Z[swz(pos8(f))];
      float2 zg = Z[swz(pos8(N2 - f))];
      float2 E = make_float2(0.5f * (zf.x + zg.x), 0.5f * (zf.y - zg.y));
      float2 O = make_float2(0.5f * (zf.y + zg.y), -0.5f * (zf.x - zg.x));
      float2 wO = cmul(tw[f], O);
      Kc[f]      = cadd(E, wO);          // K[f]
      Kc[N2 - f] = cconj(csub(E, wO));   // K[8192-f]
    }
  }
}

// ---------- conv: one (b,c) row per WG; 64 KB LDS -> 2 WGs/CU ----------
__global__ __launch_bounds__(BLK) void conv_kernel(
    const float* __restrict__ x, const float2* __restrict__ Kf,
    const float* __restrict__ bias, const float2* __restrict__ tw,
    float* __restrict__ out)
{
  extern __shared__ float2 Z[];
  const int tid = threadIdx.x;
  const int c = blockIdx.x % CCH;
  const int b = blockIdx.x / CCH;
  const float2* x2 = (const float2*)(x + (size_t)(b * CCH + c) * L_SEQ);

  // load + fused radix-2 DIF
#pragma unroll
  for (int i = tid; i < N4; i += BLK) {
    float2 v = x2[i];
    Z[swz(i)] = v;
    Z[swz(i + N4)] = cmul(v, tw[2 * i]);
  }
  __syncthreads();
  fft4k2_fwd(Z, tw, tid);

  // unpack X, multiply by K, repack spectrum of w = y_even + i*y_odd
  const float2* Kc = Kf + (size_t)c * N2;
  const float scale = 1.0f / (float)NFFT;
#pragma unroll
  for (int s2 = 0; s2 < 8; ++s2) {
    const int f = tid + s2 * BLK;
    if (f == 0) {
      float2 z0 = Z[swz(0)];
      float2 k0 = Kc[0];
      float Y0 = (z0.x + z0.y) * k0.x * scale;   // Y[0]
      float Y8 = (z0.x - z0.y) * k0.y * scale;   // Y[8192]
      Z[swz(0)] = make_float2(0.5f * (Y0 + Y8), 0.5f * (Y0 - Y8));
      float2 z4 = Z[swz(2)];
      float2 k4 = Kc[N4];
      float2 Y4 = cmul(make_float2(z4.x, -z4.y), k4);
      Y4.x *= scale; Y4.y *= scale;
      Z[swz(2)] = cconj(Y4);                      // W[4096]
    } else {
      const int p  = swz(pos8(f));
      const int pq = swz(pos8(N2 - f));
      float2 zf = Z[p], zg = Z[pq];
      float2 E = make_float2(0.5f * (zf.x + zg.x), 0.5f * (zf.y - zg.y));
      float2 O = make_float2(0.5f * (zf.y + zg.y), -0.5f * (zf.x - zg.x));
      float2 w = tw[f];
      float2 wO = cmul(w, O);
      float2 P = cadd(E, wO);                     // X[f]
      float2 M = csub(E, wO);                     // conj(X[8192-f])
      float2 Yf  = cmul(P, Kc[f]);
      float2 Ygc = cmul(M, cconj(Kc[N2 - f]));    // conj(Y[8192-f])
      Yf.x *= scale; Yf.y *= scale; Ygc.x *= scale; Ygc.y *= scale;
      float2 A  = make_float2(0.5f * (Yf.x + Ygc.x), 0.5f * (Yf.y + Ygc.y));
      float2 Bc = make_float2(0.5f * (Yf.x - Ygc.x), 0.5f * (Yf.y - Ygc.y));
      float2 cb  = cmul(cconj(w), Bc);
      Z[p]  = make_float2(A.x - cb.y, A.y + cb.x);     // W[f] = A + i*conj(w)*Bc
      float2 cb2 = cmul(w, cconj(Bc));
      Z[pq] = make_float2(A.x - cb2.y, -A.y + cb2.x);  // W[g] = conj(A) + i*w*conj(Bc)
    }
  }
  __syncthreads();
  fft4k2_inv(Z, tw, tid);

  // fused final radix-2 DIT (low half only) + epilogue, float2 stores
  const float bc = bias[c];
  float2* o2 = (float2*)(out + (size_t)(b * CCH + c) * L_SEQ);
#pragma unroll
  for (int i = tid; i < N4; i += BLK) {
    float2 a = Z[swz(i)];
    float2 bb = cmul(Z[swz(i + N4)], cconj(tw[2 * i]));
    float2 xv = x2[i];
    o2[i] = make_float2(a.x + bb.x + xv.x * bc, a.y + bb.y + xv.y * bc);
  }
}

extern "C" void kernel_launch(void* const* d_in, const int* in_sizes, int n_in,
                              void* d_out, int out_size, void* d_ws, size_t ws_size,
                              hipStream_t stream) {
  const float* x      = (const float*)d_in[0];
  const float* bias   = (const float*)d_in[1];
  const float* z      = (const float*)d_in[2];
  const float* t      = (const float*)d_in[3];
  const float* deltas = (const float*)d_in[4];
  const float* freq   = (const float*)d_in[5];
  const float* w0     = (const float*)d_in[6];
  const float* b0     = (const float*)d_in[7];
  const float* w1     = (const float*)d_in[8];
  const float* b1     = (const float*)d_in[9];
  const float* w2     = (const float*)d_in[10];
  const float* b2     = (const float*)d_in[11];
  const float* wout   = (const float*)d_in[12];
  float* out = (float*)d_out;

  // workspace layout: [tw 128KB][h 2MB][kfilt 24MB][Kf 48MB]
  const size_t tw_b    = (size_t)NFFT * sizeof(float2);
  const size_t h_b     = (size_t)ODIM * L_SEQ * sizeof(float);
  const size_t kfilt_b = (size_t)CCH * L_SEQ * sizeof(float);

  float2* tw    = (float2*)d_ws;
  float*  h     = (float*)((char*)d_ws + tw_b);
  float*  kfilt = (float*)((char*)d_ws + tw_b + h_b);
  float2* Kf    = (float2*)((char*)d_ws + tw_b + h_b + kfilt_b);

  twiddle_kernel<<<NFFT / 256, 256, 0, stream>>>(tw);
  mlp_kernel<<<L_SEQ / 64, 64, 0, stream>>>(z, freq, w0, b0, w1, b1, w2, b2, h);
  kout_kernel<<<(L_SEQ / KT_L) * (CCH / KT_C), KT_L, 0, stream>>>(h, wout, t, deltas, kfilt);

  const size_t lds = (size_t)N2 * sizeof(float2);   // 64 KB
  hipFuncSetAttribute(reinterpret_cast<const void*>(kfft_kernel),
                      hipFuncAttributeMaxDynamicSharedMemorySize, lds);
  hipFuncSetAttribute(reinterpret_cast<const void*>(conv_kernel),
                      hipFuncAttributeMaxDynamicSharedMemorySize, lds);
  kfft_kernel<<<CCH, BLK, lds, stream>>>(kfilt, tw, Kf);
  conv_kernel<<<BB * CCH, BLK, lds, stream>>>(x, Kf, bias, tw, out);
}